// Round 1
// baseline (1481.109 us; speedup 1.0000x reference)
//
#include <hip/hip_runtime.h>
#include <math.h>

// Problem constants (from reference)
#define DIM_    128
#define QH_     16
#define KVH_    4
#define GRP_    4          // QH_/KVH_
#define WIN_    512
#define BATCH_  4
#define SEQ_    2048
#define QKV_LD  3072       // (QH_+2*KVH_)*DIM_
#define ATT_LD  2048       // QH_*DIM_

// ---------------- fp32 tiled GEMM: C[M,N] = A[M,K] @ B[K,N] (row-major) -----
// BM=BN=64, BK=16, 256 threads, 4x4 register tile per thread.
template<int BM, int BN, int BK>
__global__ __launch_bounds__(256) void gemm_f32(
    const float* __restrict__ A, const float* __restrict__ B,
    float* __restrict__ C, int M, int N, int K)
{
    __shared__ float As[BK][BM + 4];   // stored transposed: As[k][m]
    __shared__ float Bs[BK][BN + 4];
    const int bm = blockIdx.y * BM;
    const int bn = blockIdx.x * BN;
    const int tid = threadIdx.x;
    const int tx = tid & 15;
    const int ty = tid >> 4;
    float acc[4][4] = {};

    for (int k0 = 0; k0 < K; k0 += BK) {
        {
            // A tile: BM x BK (64x16), one float4 per thread
            const int r = tid >> 2, c = (tid & 3) << 2;
            float4 a = *(const float4*)(A + (size_t)(bm + r) * K + k0 + c);
            As[c + 0][r] = a.x; As[c + 1][r] = a.y;
            As[c + 2][r] = a.z; As[c + 3][r] = a.w;
            // B tile: BK x BN (16x64), one float4 per thread
            const int kk = tid >> 4, nn = (tid & 15) << 2;
            *(float4*)&Bs[kk][nn] =
                *(const float4*)(B + (size_t)(k0 + kk) * N + bn + nn);
        }
        __syncthreads();
        #pragma unroll
        for (int k = 0; k < BK; ++k) {
            const float4 av = *(const float4*)&As[k][ty << 2];
            const float4 bv = *(const float4*)&Bs[k][tx << 2];
            const float a_[4] = {av.x, av.y, av.z, av.w};
            const float b_[4] = {bv.x, bv.y, bv.z, bv.w};
            #pragma unroll
            for (int i = 0; i < 4; ++i)
                #pragma unroll
                for (int j = 0; j < 4; ++j)
                    acc[i][j] = fmaf(a_[i], b_[j], acc[i][j]);
        }
        __syncthreads();
    }
    #pragma unroll
    for (int i = 0; i < 4; ++i) {
        float4 v = make_float4(acc[i][0], acc[i][1], acc[i][2], acc[i][3]);
        *(float4*)(C + (size_t)(bm + (ty << 2) + i) * N + bn + (tx << 2)) = v;
    }
}

// ---------------- Attention --------------------------------------------------
// One block (256 threads) per (b, h, 16-query tile).
// Sliding window 512 => per-tile key range [max(0,q0-512), q0+16) : <=528 keys,
// 16-aligned on both ends -> exact 16-key chunks, no partial masking on loads.
// Full score rows kept in LDS (16 x <=528), two-pass softmax (max, sum), then PV.
__global__ __launch_bounds__(256) void attn_kernel(
    const float* __restrict__ qkv, float* __restrict__ att)
{
    const int qt = blockIdx.x;           // 0..127
    const int h  = blockIdx.y;           // 0..15
    const int b  = blockIdx.z;           // 0..3
    const int q0 = qt << 4;
    const int tid = threadIdx.x;
    const int i  = tid >> 4;             // query-in-tile 0..15
    const int l  = tid & 15;             // lane-in-row  0..15

    __shared__ float Qs[16][132];        // +4 pad: 2-way banks (free)
    __shared__ float Ks[16][132];        // reused for V chunks
    __shared__ float Sc[16][545];        // score rows, cols 0..nkey-1
    __shared__ float red[16][16];        // row-reduction scratch

    const float scale = 0.08838834764831845f;           // 1/sqrt(128)
    const float slope = exp2f(-0.5f * (float)(h + 1));  // alibi slope
    const size_t bbase = (size_t)b * SEQ_ * QKV_LD;
    const int qcol = h * DIM_;
    const int kcol = (QH_ + (h >> 2)) * DIM_;
    const int vcol = (QH_ + KVH_ + (h >> 2)) * DIM_;

    // ---- load Q tile (16 x 128): 8 floats/thread
    {
        const int r = tid >> 4, c = (tid & 15) << 3;
        const float* src = qkv + bbase + (size_t)(q0 + r) * QKV_LD + qcol + c;
        *(float4*)&Qs[r][c]     = *(const float4*)(src);
        *(float4*)&Qs[r][c + 4] = *(const float4*)(src + 4);
    }

    const int jbase  = max(0, q0 - WIN_);
    const int nkey   = q0 + 16 - jbase;      // multiple of 16, <=528
    const int nchunk = nkey >> 4;

    // ---- pass 1: scores
    for (int ch = 0; ch < nchunk; ++ch) {
        const int j0 = jbase + (ch << 4);
        {
            const int r = tid >> 4, c = (tid & 15) << 3;
            const float* src = qkv + bbase + (size_t)(j0 + r) * QKV_LD + kcol + c;
            *(float4*)&Ks[r][c]     = *(const float4*)(src);
            *(float4*)&Ks[r][c + 4] = *(const float4*)(src + 4);
        }
        __syncthreads();
        {
            float s = 0.f;
            #pragma unroll
            for (int d = 0; d < DIM_; d += 4) {
                const float4 qv = *(const float4*)&Qs[i][d];
                const float4 kv = *(const float4*)&Ks[l][d];
                s = fmaf(qv.x, kv.x, s); s = fmaf(qv.y, kv.y, s);
                s = fmaf(qv.z, kv.z, s); s = fmaf(qv.w, kv.w, s);
            }
            const int j = j0 + l, qi = q0 + i;
            const bool valid = (j <= qi) && (qi - j <= WIN_);
            Sc[i][(j0 - jbase) + l] =
                valid ? fmaf(s, scale, slope * (float)(qi - j)) : -INFINITY;
        }
        __syncthreads();
    }

    // ---- pass 2: softmax over each row (cols 0..nkey-1)
    float m = -INFINITY;
    for (int c = l; c < nkey; c += 16) m = fmaxf(m, Sc[i][c]);
    red[i][l] = m;
    __syncthreads();
    m = red[i][0];
    #pragma unroll
    for (int t = 1; t < 16; ++t) m = fmaxf(m, red[i][t]);
    __syncthreads();
    float sum = 0.f;
    for (int c = l; c < nkey; c += 16) {
        const float e = __expf(Sc[i][c] - m);
        Sc[i][c] = e;
        sum += e;
    }
    red[i][l] = sum;
    __syncthreads();
    sum = 0.f;
    #pragma unroll
    for (int t = 0; t < 16; ++t) sum += red[i][t];
    const float inv = 1.f / sum;
    for (int c = l; c < nkey; c += 16) Sc[i][c] *= inv;
    __syncthreads();

    // ---- pass 3: O = P @ V ; thread owns (query i, dims l*8 .. l*8+7)
    float acc[8] = {};
    for (int ch = 0; ch < nchunk; ++ch) {
        const int j0 = jbase + (ch << 4);
        {
            const int r = tid >> 4, c = (tid & 15) << 3;
            const float* src = qkv + bbase + (size_t)(j0 + r) * QKV_LD + vcol + c;
            *(float4*)&Ks[r][c]     = *(const float4*)(src);
            *(float4*)&Ks[r][c + 4] = *(const float4*)(src + 4);
        }
        __syncthreads();
        #pragma unroll
        for (int jj = 0; jj < 16; ++jj) {
            const float p = Sc[i][(ch << 4) + jj];
            const float4 v0 = *(const float4*)&Ks[jj][(l << 3)];
            const float4 v1 = *(const float4*)&Ks[jj][(l << 3) + 4];
            acc[0] = fmaf(p, v0.x, acc[0]); acc[1] = fmaf(p, v0.y, acc[1]);
            acc[2] = fmaf(p, v0.z, acc[2]); acc[3] = fmaf(p, v0.w, acc[3]);
            acc[4] = fmaf(p, v1.x, acc[4]); acc[5] = fmaf(p, v1.y, acc[5]);
            acc[6] = fmaf(p, v1.z, acc[6]); acc[7] = fmaf(p, v1.w, acc[7]);
        }
        __syncthreads();
    }

    // ---- write O: att[b][q0+i][h*128 + l*8 .. +7]
    float* dst = att + (size_t)(b * SEQ_ + q0 + i) * ATT_LD + h * DIM_ + (l << 3);
    *(float4*)dst       = make_float4(acc[0], acc[1], acc[2], acc[3]);
    *(float4*)(dst + 4) = make_float4(acc[4], acc[5], acc[6], acc[7]);
}

// ---------------- launch -----------------------------------------------------
extern "C" void kernel_launch(void* const* d_in, const int* in_sizes, int n_in,
                              void* d_out, int out_size, void* d_ws, size_t ws_size,
                              hipStream_t stream)
{
    const float* x     = (const float*)d_in[0];   // (4,2048,128)
    const float* Wqkv  = (const float*)d_in[1];   // (128,3072)
    const float* Wproj = (const float*)d_in[2];   // (2048,128)
    float* out = (float*)d_out;                   // (4,2048,128)

    float* qkv = (float*)d_ws;                              // 8192*3072 f32 (96 MiB)
    float* att = qkv + (size_t)8192 * QKV_LD;               // 8192*2048 f32 (64 MiB)

    const dim3 blk(256);

    // qkv = x @ Wqkv : M=8192, K=128, N=3072
    gemm_f32<64, 64, 16><<<dim3(QKV_LD / 64, 8192 / 64), blk, 0, stream>>>(
        x, Wqkv, qkv, 8192, QKV_LD, DIM_);

    // attention
    attn_kernel<<<dim3(SEQ_ / 16, QH_, BATCH_), blk, 0, stream>>>(qkv, att);

    // out = att @ Wproj : M=8192, K=2048, N=128
    gemm_f32<64, 64, 16><<<dim3(DIM_ / 64, 8192 / 64), blk, 0, stream>>>(
        att, Wproj, out, 8192, DIM_, ATT_LD);
}

// Round 3
// 507.157 us; speedup vs baseline: 2.9204x; 2.9204x over previous
//
#include <hip/hip_runtime.h>
#include <math.h>

#define DIM_    128
#define QH_     16
#define KVH_    4
#define WIN_    512
#define BATCH_  4
#define SEQ_    2048
#define QKV_LD  3072
#define ATT_LD  2048

typedef __attribute__((ext_vector_type(8))) short short8;
typedef __attribute__((ext_vector_type(4))) float f32x4;
typedef unsigned short u16;
typedef unsigned int u32;

__device__ __forceinline__ u16 f2bf(float f) {        // RNE, finite inputs
    u32 u = __float_as_uint(f);
    u += 0x7fff + ((u >> 16) & 1);
    return (u16)(u >> 16);
}
__device__ __forceinline__ float bf2f(u16 u) {
    return __uint_as_float(((u32)u) << 16);
}

// ---------- GEMM1: qkv = x @ Wqkv (fp32 compute), epilogue -> bf16.
// Q/K cols (<2560) -> row-major qkvb[8192][3072]; V cols -> transposed
// vg[b][kvh][d][seq] bf16.
__global__ __launch_bounds__(256) void gemm_qkv(
    const float* __restrict__ A, const float* __restrict__ B,
    u16* __restrict__ qkvb, u16* __restrict__ vg)
{
    const int K = DIM_, N = QKV_LD;
    __shared__ float As[16][68];
    __shared__ float Bs[16][68];
    const int bm = blockIdx.y * 64;
    const int bn = blockIdx.x * 64;
    const int tid = threadIdx.x;
    const int tx = tid & 15, ty = tid >> 4;
    float acc[4][4] = {};

    for (int k0 = 0; k0 < K; k0 += 16) {
        {
            const int r = tid >> 2, c = (tid & 3) << 2;
            float4 a = *(const float4*)(A + (size_t)(bm + r) * K + k0 + c);
            As[c + 0][r] = a.x; As[c + 1][r] = a.y;
            As[c + 2][r] = a.z; As[c + 3][r] = a.w;
            const int kk = tid >> 4, nn = (tid & 15) << 2;
            *(float4*)&Bs[kk][nn] =
                *(const float4*)(B + (size_t)(k0 + kk) * N + bn + nn);
        }
        __syncthreads();
        #pragma unroll
        for (int k = 0; k < 16; ++k) {
            const float4 av = *(const float4*)&As[k][ty << 2];
            const float4 bv = *(const float4*)&Bs[k][tx << 2];
            const float a_[4] = {av.x, av.y, av.z, av.w};
            const float b_[4] = {bv.x, bv.y, bv.z, bv.w};
            #pragma unroll
            for (int i = 0; i < 4; ++i)
                #pragma unroll
                for (int j = 0; j < 4; ++j)
                    acc[i][j] = fmaf(a_[i], b_[j], acc[i][j]);
        }
        __syncthreads();
    }
    if (bn < 2560) {
        #pragma unroll
        for (int i = 0; i < 4; ++i) {
            ushort4 o;
            o.x = f2bf(acc[i][0]); o.y = f2bf(acc[i][1]);
            o.z = f2bf(acc[i][2]); o.w = f2bf(acc[i][3]);
            *(ushort4*)(qkvb + (size_t)(bm + (ty << 2) + i) * QKV_LD + bn + (tx << 2)) = o;
        }
    } else {
        const int m0 = bm + (ty << 2);
        const int bb = m0 >> 11;
        const int s0 = m0 & 2047;
        const int ncol = bn - 2560 + (tx << 2);   // 0..511
        const int kvh = ncol >> 7;
        const int d0  = ncol & 127;
        u16* base = vg + (size_t)(bb * KVH_ + kvh) * DIM_ * SEQ_;
        #pragma unroll
        for (int j = 0; j < 4; ++j) {
            ushort4 o;
            o.x = f2bf(acc[0][j]); o.y = f2bf(acc[1][j]);
            o.z = f2bf(acc[2][j]); o.w = f2bf(acc[3][j]);
            *(ushort4*)(base + (size_t)(d0 + j) * SEQ_ + s0) = o;
        }
    }
}

// ---------- GEMM2: out = att @ Wproj (fp32) ----------
__global__ __launch_bounds__(256) void gemm_f32(
    const float* __restrict__ A, const float* __restrict__ B,
    float* __restrict__ C, int M, int N, int K)
{
    __shared__ float As[16][68];
    __shared__ float Bs[16][68];
    const int bm = blockIdx.y * 64;
    const int bn = blockIdx.x * 64;
    const int tid = threadIdx.x;
    const int tx = tid & 15, ty = tid >> 4;
    float acc[4][4] = {};

    for (int k0 = 0; k0 < K; k0 += 16) {
        {
            const int r = tid >> 2, c = (tid & 3) << 2;
            float4 a = *(const float4*)(A + (size_t)(bm + r) * K + k0 + c);
            As[c + 0][r] = a.x; As[c + 1][r] = a.y;
            As[c + 2][r] = a.z; As[c + 3][r] = a.w;
            const int kk = tid >> 4, nn = (tid & 15) << 2;
            *(float4*)&Bs[kk][nn] =
                *(const float4*)(B + (size_t)(k0 + kk) * N + bn + nn);
        }
        __syncthreads();
        #pragma unroll
        for (int k = 0; k < 16; ++k) {
            const float4 av = *(const float4*)&As[k][ty << 2];
            const float4 bv = *(const float4*)&Bs[k][tx << 2];
            const float a_[4] = {av.x, av.y, av.z, av.w};
            const float b_[4] = {bv.x, bv.y, bv.z, bv.w};
            #pragma unroll
            for (int i = 0; i < 4; ++i)
                #pragma unroll
                for (int j = 0; j < 4; ++j)
                    acc[i][j] = fmaf(a_[i], b_[j], acc[i][j]);
        }
        __syncthreads();
    }
    #pragma unroll
    for (int i = 0; i < 4; ++i) {
        float4 v = make_float4(acc[i][0], acc[i][1], acc[i][2], acc[i][3]);
        *(float4*)(C + (size_t)(bm + (ty << 2) + i) * N + bn + (tx << 2)) = v;
    }
}

// ---------- MFMA attention -------------------------------------------------
// Block = 256 threads (4 waves) per (b, h, 16-query tile).
// Scores stored in LDS as bf16 RESIDUALS relative to est(q) = slope*min(q,WIN)
// (upper-bound of the row max) -- keeps the values that matter at O(1)
// magnitude so bf16 rounding in the exponent is ~0.004, not ~1.0.
__global__ __launch_bounds__(256) void attn_mfma(
    const u16* __restrict__ qkvb, const u16* __restrict__ vg,
    float* __restrict__ att)
{
    const int qt = blockIdx.x, h = blockIdx.y, b = blockIdx.z;
    const int q0 = qt << 4;
    const int tid = threadIdx.x;
    const int wv   = tid >> 6;
    const int lane = tid & 63;
    const int lr   = lane & 15;
    const int quad = lane >> 4;

    __shared__ u16  Sc[16][568];   // bf16 score residuals / P
    __shared__ float sinv[16];

    const int   kvh   = h >> 2;
    const float scale = 0.08838834764831845f;       // 1/sqrt(128)
    const float slope = exp2f(-0.5f * (float)(h + 1));
    const int   jbase = max(0, q0 - WIN_);
    const int   nkey  = q0 + 16 - jbase;            // multiple of 16, <=528
    const int   nchunk = nkey >> 4;
    const int   nslice = (nkey + 31) >> 5;          // 32-key PV slices, <=17
    const int   jend  = q0 + 16;
    const size_t rowb = (size_t)b * SEQ_;

    // ---- Q A-frags (held in regs): A[m=lr][k=quad*8+j+32s]
    short8 qf[4];
    {
        const u16* qp = qkvb + (rowb + q0 + lr) * QKV_LD + h * DIM_ + quad * 8;
        qf[0] = *(const short8*)(qp);
        qf[1] = *(const short8*)(qp + 32);
        qf[2] = *(const short8*)(qp + 64);
        qf[3] = *(const short8*)(qp + 96);
    }

    // ---- QK^T: chunk-parallel across waves, no LDS staging
    for (int ch = wv; ch < nchunk; ch += 4) {
        const int jk = jbase + (ch << 4);
        const u16* kp = qkvb + (rowb + jk + lr) * QKV_LD + (QH_ + kvh) * DIM_ + quad * 8;
        short8 k0 = *(const short8*)(kp);
        short8 k1 = *(const short8*)(kp + 32);
        short8 k2 = *(const short8*)(kp + 64);
        short8 k3 = *(const short8*)(kp + 96);
        f32x4 c = {0.f, 0.f, 0.f, 0.f};
        c = __builtin_amdgcn_mfma_f32_16x16x32_bf16(qf[0], k0, c, 0, 0, 0);
        c = __builtin_amdgcn_mfma_f32_16x16x32_bf16(qf[1], k1, c, 0, 0, 0);
        c = __builtin_amdgcn_mfma_f32_16x16x32_bf16(qf[2], k2, c, 0, 0, 0);
        c = __builtin_amdgcn_mfma_f32_16x16x32_bf16(qf[3], k3, c, 0, 0, 0);
        const int j = jk + lr;
        #pragma unroll
        for (int r = 0; r < 4; ++r) {
            const int q = q0 + quad * 4 + r;       // C row = quad*4+reg
            const int rel = q - j;
            const int relmax = (q < WIN_) ? q : WIN_;   // max rel over this row
            // residual = scale*qk + slope*(rel - relmax)  (shift-invariant softmax)
            float v = (rel >= 0 && rel <= WIN_)
                          ? fmaf(c[r], scale, slope * (float)(rel - relmax))
                          : -INFINITY;
            Sc[quad * 4 + r][(ch << 4) + lr] = f2bf(v);
        }
    }
    __syncthreads();

    // ---- softmax per row; reductions via 16-wide shfl (rows are 16-thread groups)
    {
        const int i = tid >> 4;
        const int l = tid & 15;
        float m = -INFINITY;
        for (int c = l; c < nkey; c += 16) m = fmaxf(m, bf2f(Sc[i][c]));
        #pragma unroll
        for (int o = 1; o < 16; o <<= 1) m = fmaxf(m, __shfl_xor(m, o, 16));
        float sum = 0.f;
        for (int c = l; c < nkey; c += 16) {
            float e = __expf(bf2f(Sc[i][c]) - m);
            Sc[i][c] = f2bf(e);
            sum += e;
        }
        for (int c = nkey + l; c < (nslice << 5); c += 16) Sc[i][c] = 0;  // zero pad for PV
        #pragma unroll
        for (int o = 1; o < 16; o <<= 1) sum += __shfl_xor(sum, o, 16);
        if (l == 0) sinv[i] = 1.0f / sum;
    }
    __syncthreads();

    // ---- P @ V: dim-parallel across waves; V^T B-frags directly from global
    f32x4 o0 = {0.f, 0.f, 0.f, 0.f}, o1 = {0.f, 0.f, 0.f, 0.f};
    const u16* vb = vg + ((size_t)(b * KVH_ + kvh) * DIM_ + wv * 32 + lr) * SEQ_;
    for (int sl = 0; sl < nslice; ++sl) {
        const int jc = (sl << 5) + quad * 8;             // col within Sc
        short8 pa = *(const short8*)&Sc[lr][jc];         // A[m=lr][k=jc..jc+7]
        const int jg = (jbase + jc < jend) ? (jbase + jc) : jbase;  // clamp OOB (P=0 there)
        short8 v0 = *(const short8*)(vb + jg);
        short8 v1 = *(const short8*)(vb + (size_t)16 * SEQ_ + jg);
        o0 = __builtin_amdgcn_mfma_f32_16x16x32_bf16(pa, v0, o0, 0, 0, 0);
        o1 = __builtin_amdgcn_mfma_f32_16x16x32_bf16(pa, v1, o1, 0, 0, 0);
    }

    // ---- epilogue: scale by 1/sum, write fp32 att
    float* ab = att + (rowb + q0 + quad * 4) * ATT_LD + h * DIM_ + wv * 32 + lr;
    #pragma unroll
    for (int r = 0; r < 4; ++r) {
        const float iv = sinv[quad * 4 + r];
        ab[(size_t)r * ATT_LD]      = o0[r] * iv;
        ab[(size_t)r * ATT_LD + 16] = o1[r] * iv;
    }
}

// ---------- launch ----------------------------------------------------------
extern "C" void kernel_launch(void* const* d_in, const int* in_sizes, int n_in,
                              void* d_out, int out_size, void* d_ws, size_t ws_size,
                              hipStream_t stream)
{
    const float* x     = (const float*)d_in[0];
    const float* Wqkv  = (const float*)d_in[1];
    const float* Wproj = (const float*)d_in[2];
    float* out = (float*)d_out;

    u16* qkvb = (u16*)d_ws;                                   // 8192*3072 bf16 (48 MB)
    u16* vg   = qkvb + (size_t)8192 * QKV_LD;                 // 4*4*128*2048 bf16 (8 MB)
    float* att = (float*)(vg + (size_t)BATCH_ * KVH_ * DIM_ * SEQ_); // 8192*2048 f32 (64 MB)

    const dim3 blk(256);

    gemm_qkv<<<dim3(QKV_LD / 64, 8192 / 64), blk, 0, stream>>>(x, Wqkv, qkvb, vg);

    attn_mfma<<<dim3(SEQ_ / 16, QH_, BATCH_), blk, 0, stream>>>(qkvb, vg, att);

    gemm_f32<<<dim3(DIM_ / 64, 8192 / 64), blk, 0, stream>>>(
        att, Wproj, out, 8192, DIM_, ATT_LD);
}